// Round 1
// baseline (281.037 us; speedup 1.0000x reference)
//
#include <hip/hip_runtime.h>

#define EMA_EPS 1e-12f

__device__ __forceinline__ float wave_reduce_sum(float v) {
    #pragma unroll
    for (int off = 32; off > 0; off >>= 1) v += __shfl_xor(v, off, 64);
    return v;
}

// ---------------------------------------------------------------------------
// Kernel A: per-row mean / std (ddof=1). One 64-lane wave per row of D floats.
// ---------------------------------------------------------------------------
__global__ __launch_bounds__(256) void ema_stats_kernel(
    const float* __restrict__ x,
    float* __restrict__ mu, float* __restrict__ sigma,
    int nrows, int d4 /* = D/4 */)
{
    int wave = (int)((blockIdx.x * blockDim.x + threadIdx.x) >> 6);
    int lane = threadIdx.x & 63;
    if (wave >= nrows) return;

    const float4* xr = (const float4*)(x + (size_t)wave * (size_t)(d4 * 4));
    float s = 0.f, sq = 0.f;
    for (int c = lane; c < d4; c += 64) {
        float4 a = xr[c];
        s  += a.x + a.y + a.z + a.w;
        sq += a.x*a.x + a.y*a.y + a.z*a.z + a.w*a.w;
    }
    s  = wave_reduce_sum(s);
    sq = wave_reduce_sum(sq);
    if (lane == 0) {
        int   n    = d4 * 4;
        float mean = s / (float)n;
        float var  = (sq - s * mean) / (float)(n - 1);
        var = fmaxf(var, 0.0f);
        mu[wave]    = mean;
        sigma[wave] = sqrtf(var);
    }
}

// ---------------------------------------------------------------------------
// Kernel B: per-batch weighted cumulative sum over S.
//   mu_cum[s]    = alpha*h_mu    + sum_{t<=s} (1-alpha)*alpha^t * mu[t]
//   sigma_cum[s] = max(alpha*h_sigma + sum_{t<=s} (1-alpha)*alpha^t * sigma[t], EPS)
// One block per batch, 256 threads, each thread owns S/256 contiguous values.
// ---------------------------------------------------------------------------
__global__ __launch_bounds__(256) void ema_scan_kernel(
    const float* __restrict__ mu, const float* __restrict__ sigma,
    const float* __restrict__ h, const float* __restrict__ alpha_logit,
    float* __restrict__ mu_cum, float* __restrict__ sigma_cum,
    float* __restrict__ h_new, int S)
{
    const int b   = blockIdx.x;
    const int tid = threadIdx.x;
    const int CHUNK = S / 256;

    const float alpha = 1.0f / (1.0f + expf(-alpha_logit[0]));
    const float one_m_a = 1.0f - alpha;
    const float l2a = log2f(alpha);

    const float* mub = mu    + (size_t)b * S;
    const float* sgb = sigma + (size_t)b * S;
    const float h_mu = h[b * 2 + 0];
    const float h_sg = h[b * 2 + 1];

    const int s0 = tid * CHUNK;
    const float w0 = one_m_a * exp2f((float)s0 * l2a);

    // Phase 1: per-thread local sums of w[s]*mu[s], w[s]*sigma[s]
    float lm = 0.f, ls = 0.f;
    {
        float w = w0;
        for (int i = 0; i < CHUNK; ++i) {
            lm += w * mub[s0 + i];
            ls += w * sgb[s0 + i];
            w *= alpha;
        }
    }

    // Phase 2: block exclusive scan of the 256 per-thread sums
    const int lane = tid & 63, wid = tid >> 6;
    float im = lm, is = ls;
    #pragma unroll
    for (int off = 1; off < 64; off <<= 1) {
        float tm = __shfl_up(im, off, 64);
        float ts = __shfl_up(is, off, 64);
        if (lane >= off) { im += tm; is += ts; }
    }
    __shared__ float wsum_m[4], wsum_s[4];
    if (lane == 63) { wsum_m[wid] = im; wsum_s[wid] = is; }
    __syncthreads();
    float base_m = 0.f, base_s = 0.f;
    for (int wp = 0; wp < wid; ++wp) { base_m += wsum_m[wp]; base_s += wsum_s[wp]; }
    const float excl_m = base_m + (im - lm);
    const float excl_s = base_s + (is - ls);

    // Phase 3: walk the chunk again with the running inclusive sum, write out
    float* mcb = mu_cum    + (size_t)b * S;
    float* scb = sigma_cum + (size_t)b * S;
    float run_m = alpha * h_mu + excl_m;
    float run_s = alpha * h_sg + excl_s;
    {
        float w = w0;
        for (int i = 0; i < CHUNK; ++i) {
            run_m += w * mub[s0 + i];
            run_s += w * sgb[s0 + i];
            mcb[s0 + i] = run_m;
            scb[s0 + i] = fmaxf(run_s, EMA_EPS);
            w *= alpha;
        }
    }
    if (tid == 255) {
        h_new[b * 2 + 0] = run_m;
        h_new[b * 2 + 1] = fmaxf(run_s, EMA_EPS);
    }
}

// ---------------------------------------------------------------------------
// Kernel C: y = (x - mu_cum[row]) / sigma_cum[row] * gamma[d] + beta[d]
// One float4 per thread.
// ---------------------------------------------------------------------------
__global__ __launch_bounds__(256) void ema_norm_kernel(
    const float* __restrict__ x,
    const float* __restrict__ mu_cum, const float* __restrict__ sigma_cum,
    const float* __restrict__ gamma, const float* __restrict__ beta,
    float* __restrict__ y, int n4, int d4_shift, int d4_mask)
{
    int gid = (int)(blockIdx.x * blockDim.x + threadIdx.x);
    if (gid >= n4) return;
    int row = gid >> d4_shift;
    int c4  = gid & d4_mask;

    float m  = mu_cum[row];
    float rs = 1.0f / sigma_cum[row];
    float4 g  = ((const float4*)gamma)[c4];
    float4 bt = ((const float4*)beta)[c4];
    float4 xv = ((const float4*)x)[gid];
    float4 yv;
    yv.x = (xv.x - m) * rs * g.x + bt.x;
    yv.y = (xv.y - m) * rs * g.y + bt.y;
    yv.z = (xv.z - m) * rs * g.z + bt.z;
    yv.w = (xv.w - m) * rs * g.w + bt.w;
    ((float4*)y)[gid] = yv;
}

extern "C" void kernel_launch(void* const* d_in, const int* in_sizes, int n_in,
                              void* d_out, int out_size, void* d_ws, size_t ws_size,
                              hipStream_t stream) {
    const float* x           = (const float*)d_in[0];
    const float* h           = (const float*)d_in[1];
    const float* gamma       = (const float*)d_in[2];
    const float* beta        = (const float*)d_in[3];
    const float* alpha_logit = (const float*)d_in[4];
    float* out = (float*)d_out;

    const int D     = in_sizes[2];          // 512
    const int B     = in_sizes[1] / 2;      // 8
    const int total = in_sizes[0];          // B*S*D
    const int S     = total / (B * D);      // 8192
    const int nrows = B * S;
    const int d4    = D / 4;

    float* mu_ws = (float*)d_ws;
    float* sg_ws = mu_ws + nrows;
    float* mc_ws = sg_ws + nrows;
    float* sc_ws = mc_ws + nrows;

    // A: stats. 4 waves/block -> 4 rows/block.
    ema_stats_kernel<<<(nrows + 3) / 4, 256, 0, stream>>>(x, mu_ws, sg_ws, nrows, d4);

    // B: scan. One block per batch; writes h_new at tail of d_out.
    ema_scan_kernel<<<B, 256, 0, stream>>>(mu_ws, sg_ws, h, alpha_logit,
                                           mc_ws, sc_ws, out + (size_t)total, S);

    // C: normalize.
    int n4 = total / 4;
    int d4_shift = __builtin_ctz(d4);
    ema_norm_kernel<<<(n4 + 255) / 256, 256, 0, stream>>>(
        x, mc_ws, sc_ws, gamma, beta, out, n4, d4_shift, d4 - 1);
}